// Round 14
// baseline (283.566 us; speedup 1.0000x reference)
//
#include <hip/hip_runtime.h>
#include <math.h>

// ---------------------------------------------------------------------------
// Transformer block (pre-LN). f32 in / f32 out (bf16-space comparison).
// Compute: bf16 MFMA, f32 accum. Workspace ~55.8 MiB.
// R14: GEMM K-loop -> BK=32 double-buffered ONE-barrier pipeline (attn-v9
//      pattern; drains overlap compute -- targets the ~350 TF GEMM stall).
//      transpose_all + LN1 merged into one prep dispatch. attn v10 frozen.
// MFMA layouts (guide m89/m91/m92/m120):
//   A-frag:  A[m=lane&15][k=quad*8+j]
//   B-frag:  BT[n=lane&15][k=quad*8+j]
//   C/D:     row = quad*4 + reg, col = lane&15
// ---------------------------------------------------------------------------

typedef unsigned short u16;
typedef __attribute__((ext_vector_type(8))) short short8;   // 8 x bf16
typedef __attribute__((ext_vector_type(4))) float f32x4;

#define TOKENS 4096
#define DIM    768
#define QKV_N  2304
#define HID    3072
#define NSEQ   2048
#define NHEAD  12
#define HDIM   64

__device__ __forceinline__ float bf2f(u16 u) {
  union { unsigned i; float f; } v; v.i = ((unsigned)u) << 16; return v.f;
}
__device__ __forceinline__ u16 f2bf(float f) {
  union { float f; unsigned i; } v; v.f = f;
  unsigned r = v.i + 0x7fffu + ((v.i >> 16) & 1u);   // RNE
  return (u16)(r >> 16);
}
__device__ __forceinline__ u16 f2bf_trunc(float f) {  // positive P values
  union { float f; unsigned i; } v; v.f = f;
  return (u16)(v.i >> 16);
}

// async global->LDS, 16B/lane. LDS dest = wave-uniform base + lane*16 (m104).
__device__ __forceinline__ void async_copy16(const u16* g, u16* l) {
  __builtin_amdgcn_global_load_lds(
      (const __attribute__((address_space(1))) unsigned int*)(unsigned long long)g,
      (__attribute__((address_space(3))) unsigned int*)(unsigned int)(unsigned long long)l,
      16, 0, 0);
}

// ---- prep: 4 weight transposes + LN1, one dispatch --------------------------
// blocks 0..1023: LN1 (4 tokens each). blocks 1024..7935: 32x32 transposes.
__global__ __launch_bounds__(256) void prep_kernel(
    const float* __restrict__ x, const float* __restrict__ g,
    const float* __restrict__ b, u16* __restrict__ h,
    const float* __restrict__ in0, u16* __restrict__ out0,   // 768x2304
    const float* __restrict__ in1, u16* __restrict__ out1,   // 768x768
    const float* __restrict__ in2, u16* __restrict__ out2,   // 768x3072
    const float* __restrict__ in3, u16* __restrict__ out3) { // 3072x768
  const int tid = threadIdx.x;
  if (blockIdx.x < 1024) {
    // ---- LN1: one wave per token, f32 input ----
    int wave = tid >> 6, lane = tid & 63;
    int token = blockIdx.x * 4 + wave;
    float v[12];
    const float4* xr = (const float4*)(x + (size_t)token * DIM);
#pragma unroll
    for (int w = 0; w < 3; w++) {
      float4 q = xr[lane + w * 64];
      v[w * 4 + 0] = q.x; v[w * 4 + 1] = q.y; v[w * 4 + 2] = q.z; v[w * 4 + 3] = q.w;
    }
    float s = 0.f;
#pragma unroll
    for (int i = 0; i < 12; i++) s += v[i];
#pragma unroll
    for (int off = 32; off > 0; off >>= 1) s += __shfl_xor(s, off);
    float mu = s * (1.0f / DIM);
    float ss = 0.f;
#pragma unroll
    for (int i = 0; i < 12; i++) { float d = v[i] - mu; ss += d * d; }
#pragma unroll
    for (int off = 32; off > 0; off >>= 1) ss += __shfl_xor(ss, off);
    float rs = rsqrtf(ss * (1.0f / DIM) + 1e-5f);
    ushort4* orow = (ushort4*)(h + (size_t)token * DIM);
    const float4* g4 = (const float4*)g;
    const float4* b4 = (const float4*)b;
#pragma unroll
    for (int w = 0; w < 3; w++) {
      float4 gq = g4[lane + w * 64], bq = b4[lane + w * 64];
      ushort4 o;
      o.x = f2bf((v[w * 4 + 0] - mu) * rs * gq.x + bq.x);
      o.y = f2bf((v[w * 4 + 1] - mu) * rs * gq.y + bq.y);
      o.z = f2bf((v[w * 4 + 2] - mu) * rs * gq.z + bq.z);
      o.w = f2bf((v[w * 4 + 3] - mu) * rs * gq.w + bq.w);
      orow[lane + w * 64] = o;
    }
    return;
  }
  // ---- weight transpose ----
  __shared__ u16 t[32][33];
  int bid = blockIdx.x - 1024, rem;
  const float* in; u16* out; int R, C;
  if (bid < 1728)      { in = in0; out = out0; R = 768;  C = 2304; rem = bid; }
  else if (bid < 2304) { in = in1; out = out1; R = 768;  C = 768;  rem = bid - 1728; }
  else if (bid < 4608) { in = in2; out = out2; R = 768;  C = 3072; rem = bid - 2304; }
  else                 { in = in3; out = out3; R = 3072; C = 768;  rem = bid - 4608; }
  int c0 = (rem % (C / 32)) * 32, r0 = (rem / (C / 32)) * 32;
  int tx = tid & 31, ty = tid >> 5;
#pragma unroll
  for (int i = 0; i < 4; i++)
    t[ty + i * 8][tx] = f2bf(in[(size_t)(r0 + ty + i * 8) * C + c0 + tx]);
  __syncthreads();
#pragma unroll
  for (int i = 0; i < 4; i++)
    out[(size_t)(c0 + ty + i * 8) * R + r0 + tx] = t[tx][ty + i * 8];
}

// ---- LayerNorm (LN2): one wave per token, bf16 input -----------------------
__global__ __launch_bounds__(256) void ln_kernel(const u16* __restrict__ xin,
                                                 const float* __restrict__ g,
                                                 const float* __restrict__ b,
                                                 u16* __restrict__ out) {
  int wave = threadIdx.x >> 6, lane = threadIdx.x & 63;
  int token = blockIdx.x * 4 + wave;
  float v[12];
  const ushort4* xr = (const ushort4*)(xin + (size_t)token * DIM);
#pragma unroll
  for (int w = 0; w < 3; w++) {
    ushort4 q = xr[lane + w * 64];
    v[w * 4 + 0] = bf2f(q.x); v[w * 4 + 1] = bf2f(q.y);
    v[w * 4 + 2] = bf2f(q.z); v[w * 4 + 3] = bf2f(q.w);
  }
  float s = 0.f;
#pragma unroll
  for (int i = 0; i < 12; i++) s += v[i];
#pragma unroll
  for (int off = 32; off > 0; off >>= 1) s += __shfl_xor(s, off);
  float mu = s * (1.0f / DIM);
  float ss = 0.f;
#pragma unroll
  for (int i = 0; i < 12; i++) { float d = v[i] - mu; ss += d * d; }
#pragma unroll
  for (int off = 32; off > 0; off >>= 1) ss += __shfl_xor(ss, off);
  float rs = rsqrtf(ss * (1.0f / DIM) + 1e-5f);

  ushort4* orow = (ushort4*)(out + (size_t)token * DIM);
  const float4* g4 = (const float4*)g;
  const float4* b4 = (const float4*)b;
#pragma unroll
  for (int w = 0; w < 3; w++) {
    float4 gq = g4[lane + w * 64], bq = b4[lane + w * 64];
    ushort4 o;
    o.x = f2bf((v[w * 4 + 0] - mu) * rs * gq.x + bq.x);
    o.y = f2bf((v[w * 4 + 1] - mu) * rs * gq.y + bq.y);
    o.z = f2bf((v[w * 4 + 2] - mu) * rs * gq.z + bq.z);
    o.w = f2bf((v[w * 4 + 3] - mu) * rs * gq.w + bq.w);
    orow[lane + w * 64] = o;
  }
}

// ---- GEMM: C[M,N] = A[M,K] * BT[N,K]^T, bf16 in, fused epilogue ------------
// BK=32, double-buffered LDS, ONE barrier per iter: barrier (drains DMA(it)
// issued last iter + protects buffer reuse) -> issue DMA(it+1) into buf^1 ->
// compute from buf cur. Same barrier count as the 2-barrier BK=64 loop but
// every drain overlaps a full compute phase (R12-proven pattern).
// EPI: 0 = qkv: Q/K cols bf16 store; V cols (>=1536) packed transposed store
//          into vtb[b*768+hd][tok] (fuses transpose_v)
//      1 = +bias(f32) + resid(f32) -> bf16 store (proj -> x1 trunk)
//      2 = +bias(f32), exact gelu -> bf16 store (fc1)
//      3 = +bias(f32) + resid(bf16) -> F32 store (fc2 -> d_out)
template <int BM, int BN, int EPI>
__global__ __launch_bounds__(256, 3) void gemm_bt(
    const u16* __restrict__ A, const u16* __restrict__ BT,
    void* __restrict__ Cout, const float* __restrict__ bias,
    const void* __restrict__ resid, int M, int N, int K,
    u16* __restrict__ vtb) {
  constexpr int MT = BM / 32, NT = BN / 32;        // mfma tiles per wave
  constexpr int ACH = BM / 16;                     // A 16-row chunks
  constexpr int CPW = (BM + BN) / 64;              // staging chunks per wave
  __shared__ __align__(16) u16 Alds[2][BM * 32];   // double-buffered panels
  __shared__ __align__(16) u16 Blds[2][BN * 32];
  const int tid = threadIdx.x;
  const int lane = tid & 63, wave = tid >> 6;
  const int wr = wave >> 1, wc = wave & 1;
  const int bm = blockIdx.y * BM, bn = blockIdx.x * BN;
  const int c16 = lane & 15, quad = lane >> 4;
  const int l4 = lane >> 2, lc = (lane & 3) * 8;

  f32x4 acc[MT][NT];
#pragma unroll
  for (int i = 0; i < MT; i++)
#pragma unroll
    for (int j = 0; j < NT; j++) acc[i][j] = (f32x4){0.f, 0.f, 0.f, 0.f};

  const u16* gsrc[CPW];
  u16* ldst[2][CPW];
#pragma unroll
  for (int c = 0; c < CPW; c++) {
    int chunk = wave * CPW + c;
    if (chunk < ACH) {
      gsrc[c] = A + (size_t)(bm + chunk * 16 + l4) * K + lc;
      ldst[0][c] = Alds[0] + chunk * 512;
      ldst[1][c] = Alds[1] + chunk * 512;
    } else {
      int bc = chunk - ACH;
      gsrc[c] = BT + (size_t)(bn + bc * 16 + l4) * K + lc;
      ldst[0][c] = Blds[0] + bc * 512;
      ldst[1][c] = Blds[1] + bc * 512;
    }
  }

  // prologue: stage k-panel 0 into buffer 0
#pragma unroll
  for (int c = 0; c < CPW; c++) async_copy16(gsrc[c], ldst[0][c]);

  const int nit = K / 32;
  for (int it = 0; it < nit; it++) {
    const int cur = it & 1;
    __syncthreads();   // drains DMA(it) (issued last iter: full compute phase
                       // to land) + all waves done reading buffer cur^1
    if (it + 1 < nit) {
      const int kk = (it + 1) * 32;
#pragma unroll
      for (int c = 0; c < CPW; c++) async_copy16(gsrc[c] + kk, ldst[cur ^ 1][c]);
    }
    short8 af[MT], bfr[NT];
#pragma unroll
    for (int mt = 0; mt < MT; mt++)
      af[mt] = *(const short8*)(Alds[cur] + (wr * (BM / 2) + mt * 16 + c16) * 32 + quad * 8);
#pragma unroll
    for (int nt = 0; nt < NT; nt++)
      bfr[nt] = *(const short8*)(Blds[cur] + (wc * (BN / 2) + nt * 16 + c16) * 32 + quad * 8);
#pragma unroll
    for (int mt = 0; mt < MT; mt++)
#pragma unroll
      for (int nt = 0; nt < NT; nt++)
        acc[mt][nt] = __builtin_amdgcn_mfma_f32_16x16x32_bf16(af[mt], bfr[nt],
                                                              acc[mt][nt], 0, 0, 0);
  }

#pragma unroll
  for (int mt = 0; mt < MT; mt++) {
#pragma unroll
    for (int nt = 0; nt < NT; nt++) {
      int col = bn + wc * (BN / 2) + nt * 16 + c16;
      float bv = (EPI != 0) ? bias[col] : 0.f;
      int row0 = bm + wr * (BM / 2) + mt * 16 + quad * 4;
      if (EPI == 0 && col >= 2 * DIM) {
        // V columns: packed transposed store vt[(b*768+hd)][tok] (tok=row)
        int b = row0 >> 11;
        ushort4 pk;
        pk.x = f2bf(acc[mt][nt][0]); pk.y = f2bf(acc[mt][nt][1]);
        pk.z = f2bf(acc[mt][nt][2]); pk.w = f2bf(acc[mt][nt][3]);
        *(ushort4*)(vtb + ((size_t)b * DIM + col - 2 * DIM) * NSEQ + (row0 & 2047)) = pk;
        continue;
      }
#pragma unroll
      for (int r = 0; r < 4; r++) {
        int row = row0 + r;
        float vv = acc[mt][nt][r];
        if (EPI == 1) {
          vv += bv + ((const float*)resid)[(size_t)row * N + col];
          ((u16*)Cout)[(size_t)row * N + col] = f2bf(vv);
        } else if (EPI == 2) {
          vv += bv;
          vv = 0.5f * vv * (1.0f + erff(vv * 0.70710678118654752f));
          ((u16*)Cout)[(size_t)row * N + col] = f2bf(vv);
        } else if (EPI == 3) {
          vv += bv + bf2f(((const u16*)resid)[(size_t)row * N + col]);
          ((float*)Cout)[(size_t)row * N + col] = vv;     // f32 final output
        } else {
          ((u16*)Cout)[(size_t)row * N + col] = f2bf(vv);
        }
      }
    }
  }
}

// ---- flash attention v10 (frozen): 4 waves x 16 q + dbuf one-barrier -------
__global__ __launch_bounds__(256) void attn_kernel(const u16* __restrict__ qkv,
                                                   const u16* __restrict__ vt,
                                                   u16* __restrict__ o) {
  const int tid = threadIdx.x;
  const int lane = tid & 63, wave = tid >> 6;      // wave 0..3
  const int c16 = lane & 15, quad = lane >> 4;
  const int qt = blockIdx.x & 31;
  const int bh = blockIdx.x >> 5;
  const int bb = bh / NHEAD, h = bh % NHEAD;
  __shared__ __align__(16) u16 Klds[2][64 * 64];   // [buf][key][d] swizzled
  __shared__ __align__(16) u16 Vtlds[2][64 * 64];  // [buf][d][key] swizzled
  __shared__ __align__(16) u16 Plds[4][16 * 64];   // per-wave P [q][key] swz
  const size_t base = (size_t)bb * NSEQ * QKV_N;
  const int q0 = qt * 64 + wave * 16;

  const u16* qp = qkv + base + (size_t)(q0 + c16) * QKV_N + h * HDIM;
  short8 qf0 = *(const short8*)(qp + quad * 8);
  short8 qf1 = *(const short8*)(qp + 32 + quad * 8);

  float Ls[4] = {0.f, 0.f, 0.f, 0.f};
  f32x4 Of[4];
#pragma unroll
  for (int dt = 0; dt < 4; dt++) Of[dt] = (f32x4){0.f, 0.f, 0.f, 0.f};

  const int srow = lane >> 3;
  const int schunk = (lane & 7) ^ srow;
  const int r0 = wave * 16;
  const u16* ksrc = qkv + base + (size_t)(r0 + srow) * QKV_N + DIM + h * HDIM + schunk * 8;
  const u16* vsrc = vt + ((size_t)bh * HDIM + r0 + srow) * NSEQ + schunk * 8;

  const int cswz0 = (quad ^ (c16 & 7)) * 8;        // frag-read swizzled chunks
  const int cswz1 = ((quad + 4) ^ (c16 & 7)) * 8;
  const float SC = 0.18033688011112042f;           // 0.125 * log2(e)

  // prologue: stage tile 0 into buffer 0
#pragma unroll
  for (int j = 0; j < 2; j++) {
    async_copy16(ksrc + (size_t)(8 * j) * QKV_N, Klds[0] + r0 * 64 + 8 * j * 64);
    async_copy16(vsrc + (size_t)(8 * j) * NSEQ, Vtlds[0] + r0 * 64 + 8 * j * 64);
  }

  for (int it = 0; it < NSEQ / 64; it++) {
    const int cur = it & 1;
    __syncthreads();   // drains DMA(it) + all waves done reading buf cur^1
    if (it + 1 < NSEQ / 64) {
      const int kt1 = (it + 1) * 64;
      u16* kd = Klds[cur ^ 1] + r0 * 64;
      u16* vd = Vtlds[cur ^ 1] + r0 * 64;
#pragma unroll
      for (int j = 0; j < 2; j++) {
        async_copy16(ksrc + (size_t)(kt1 + 8 * j) * QKV_N, kd + 8 * j * 64);
        async_copy16(vsrc + (size_t)(8 * j) * NSEQ + kt1, vd + 8 * j * 64);
      }
    }

    // S = Q K^T : 4 key-tiles of 16
    f32x4 S[4];
#pragma unroll
    for (int nt = 0; nt < 4; nt++) {
      S[nt] = (f32x4){0.f, 0.f, 0.f, 0.f};
      const u16* krow = Klds[cur] + (nt * 16 + c16) * 64;
      short8 ka = *(const short8*)(krow + cswz0);
      short8 kb = *(const short8*)(krow + cswz1);
      S[nt] = __builtin_amdgcn_mfma_f32_16x16x32_bf16(qf0, ka, S[nt], 0, 0, 0);
      S[nt] = __builtin_amdgcn_mfma_f32_16x16x32_bf16(qf1, kb, S[nt], 0, 0, 0);
    }

    // fixed-max softmax: p = 2^(S*SC); per-lane L partials, no shuffles
    u16* pl = Plds[wave];
    const int el = c16 & 7, ch = c16 >> 3;
#pragma unroll
    for (int r = 0; r < 4; r++) {
      float p0 = __builtin_amdgcn_exp2f(S[0][r] * SC);
      float p1 = __builtin_amdgcn_exp2f(S[1][r] * SC);
      float p2 = __builtin_amdgcn_exp2f(S[2][r] * SC);
      float p3 = __builtin_amdgcn_exp2f(S[3][r] * SC);
      Ls[r] += (p0 + p1) + (p2 + p3);
      u16* pr = pl + (quad * 4 + r) * 64;
      const int r7 = (quad * 4 + r) & 7;
      pr[((0 + ch) ^ r7) * 8 + el] = f2bf_trunc(p0);
      pr[((2 + ch) ^ r7) * 8 + el] = f2bf_trunc(p1);
      pr[((4 + ch) ^ r7) * 8 + el] = f2bf_trunc(p2);
      pr[((6 + ch) ^ r7) * 8 + el] = f2bf_trunc(p3);
    }
    // no barrier: Plds[wave] is same-wave only; DS ops execute in order

    // PV: A = P[16q x 64keys] (2 k-chunks), B^T = Vt[d][key] b128 frags
    short8 pf0 = *(const short8*)(pl + c16 * 64 + cswz0);
    short8 pf1 = *(const short8*)(pl + c16 * 64 + cswz1);
#pragma unroll
    for (int dt = 0; dt < 4; dt++) {
      const u16* vrow = Vtlds[cur] + (dt * 16 + c16) * 64;
      short8 va = *(const short8*)(vrow + cswz0);
      short8 vb = *(const short8*)(vrow + cswz1);
      Of[dt] = __builtin_amdgcn_mfma_f32_16x16x32_bf16(pf0, va, Of[dt], 0, 0, 0);
      Of[dt] = __builtin_amdgcn_mfma_f32_16x16x32_bf16(pf1, vb, Of[dt], 0, 0, 0);
    }
  }

  // row totals: reduce per-lane partials over the 16 lanes sharing each row
#pragma unroll
  for (int r = 0; r < 4; r++) {
    float t = Ls[r];
    t += __shfl_xor(t, 1); t += __shfl_xor(t, 2);
    t += __shfl_xor(t, 4); t += __shfl_xor(t, 8);
    Ls[r] = t;
  }

#pragma unroll
  for (int dt = 0; dt < 4; dt++)
#pragma unroll
    for (int r = 0; r < 4; r++) {
      int token = q0 + quad * 4 + r;
      float val = Of[dt][r] / Ls[r];
      o[(size_t)(bb * NSEQ + token) * DIM + h * HDIM + dt * 16 + c16] = f2bf(val);
    }
}

// ---------------------------------------------------------------------------
extern "C" void kernel_launch(void* const* d_in, const int* in_sizes, int n_in,
                              void* d_out, int out_size, void* d_ws, size_t ws_size,
                              hipStream_t stream) {
  (void)in_sizes; (void)n_in; (void)out_size; (void)ws_size;
  const float* x      = (const float*)d_in[0];
  const float* ln1_g  = (const float*)d_in[1];
  const float* ln1_b  = (const float*)d_in[2];
  const float* w_qkv  = (const float*)d_in[3];
  const float* w_proj = (const float*)d_in[4];
  const float* b_proj = (const float*)d_in[5];
  const float* ln2_g  = (const float*)d_in[6];
  const float* ln2_b  = (const float*)d_in[7];
  const float* w_fc1  = (const float*)d_in[8];
  const float* b_fc1  = (const float*)d_in[9];
  const float* w_fc2  = (const float*)d_in[10];
  const float* b_fc2  = (const float*)d_in[11];
  float* out = (float*)d_out;   // f32 output (reference dtype)

  // ---- workspace layout: ~55.8 MiB total ----
  char* p = (char*)d_ws;
  u16* h_bf   = (u16*)p; p += (size_t)TOKENS * DIM * 2;     //  h, then h2
  u16* qkv_bf = (u16*)p; p += (size_t)TOKENS * QKV_N * 2;
  u16* o_bf   = (u16*)p; p += (size_t)TOKENS * DIM * 2;
  u16* x1_bf  = (u16*)p; p += (size_t)TOKENS * DIM * 2;     //  trunk
  u16* wprojT = (u16*)p; p += (size_t)DIM * DIM * 2;
  u16* wfc1T  = (u16*)p; p += (size_t)HID * DIM * 2;
  u16* wfc2T  = (u16*)p; p += (size_t)DIM * HID * 2;
  u16* wqkvT  = (u16*)p; p += (size_t)QKV_N * DIM * 2;
  u16* vtb    = (u16*)p; p += (size_t)TOKENS * DIM * 2;     //  V transposed
  u16* m_bf   = qkv_bf;  // fc1 out [4096,3072] overlays dead [qkv|o] exactly

  prep_kernel<<<dim3(1024 + 6912), 256, 0, stream>>>(
      x, ln1_g, ln1_b, h_bf,
      w_qkv, wqkvT, w_proj, wprojT, w_fc1, wfc1T, w_fc2, wfc2T);

  gemm_bt<64, 128, 0><<<dim3(QKV_N / 128, TOKENS / 64), 256, 0, stream>>>(
      h_bf, wqkvT, qkv_bf, nullptr, nullptr, TOKENS, QKV_N, DIM, vtb);
  attn_kernel<<<dim3(2 * NHEAD * (NSEQ / 64)), 256, 0, stream>>>(qkv_bf, vtb, o_bf);
  gemm_bt<64, 128, 1><<<dim3(DIM / 128, TOKENS / 64), 256, 0, stream>>>(
      o_bf, wprojT, x1_bf, b_proj, x, TOKENS, DIM, DIM, nullptr);
  ln_kernel<<<TOKENS / 4, 256, 0, stream>>>(x1_bf, ln2_g, ln2_b, h_bf);
  gemm_bt<128, 128, 2><<<dim3(HID / 128, TOKENS / 128), 256, 0, stream>>>(
      h_bf, wfc1T, m_bf, b_fc1, nullptr, TOKENS, HID, DIM, nullptr);
  gemm_bt<64, 128, 3><<<dim3(DIM / 128, TOKENS / 64), 256, 0, stream>>>(
      m_bf, wfc2T, out, b_fc2, x1_bf, TOKENS, DIM, HID, nullptr);
}

// Round 15
// 270.184 us; speedup vs baseline: 1.0495x; 1.0495x over previous
//
#include <hip/hip_runtime.h>
#include <math.h>

// ---------------------------------------------------------------------------
// Transformer block (pre-LN). f32 in / f32 out (bf16-space comparison).
// Compute: bf16 MFMA, f32 accum. Workspace ~55.8 MiB.
// R15: XCD-locality swizzles. attn: head-major block order (24 | blocks ->
//      all q-tiles of a head on one XCD; KV L2-resident). GEMM: A-local flat
//      grid (by = b % (M/BM), multiples of 8 -> A panels L2-resident/XCD).
//      GEMM reverted to R13 BK=64 2-barrier (R14 dbuf regressed). Prep merge
//      kept. attn v10 otherwise frozen.
// MFMA layouts (guide m89/m91/m92/m120):
//   A-frag:  A[m=lane&15][k=quad*8+j]
//   B-frag:  BT[n=lane&15][k=quad*8+j]
//   C/D:     row = quad*4 + reg, col = lane&15
// ---------------------------------------------------------------------------

typedef unsigned short u16;
typedef __attribute__((ext_vector_type(8))) short short8;   // 8 x bf16
typedef __attribute__((ext_vector_type(4))) float f32x4;

#define TOKENS 4096
#define DIM    768
#define QKV_N  2304
#define HID    3072
#define NSEQ   2048
#define NHEAD  12
#define HDIM   64

__device__ __forceinline__ float bf2f(u16 u) {
  union { unsigned i; float f; } v; v.i = ((unsigned)u) << 16; return v.f;
}
__device__ __forceinline__ u16 f2bf(float f) {
  union { float f; unsigned i; } v; v.f = f;
  unsigned r = v.i + 0x7fffu + ((v.i >> 16) & 1u);   // RNE
  return (u16)(r >> 16);
}
__device__ __forceinline__ u16 f2bf_trunc(float f) {  // positive P values
  union { float f; unsigned i; } v; v.f = f;
  return (u16)(v.i >> 16);
}

// async global->LDS, 16B/lane. LDS dest = wave-uniform base + lane*16 (m104).
__device__ __forceinline__ void async_copy16(const u16* g, u16* l) {
  __builtin_amdgcn_global_load_lds(
      (const __attribute__((address_space(1))) unsigned int*)(unsigned long long)g,
      (__attribute__((address_space(3))) unsigned int*)(unsigned int)(unsigned long long)l,
      16, 0, 0);
}

// ---- prep: 4 weight transposes + LN1, one dispatch --------------------------
// blocks 0..1023: LN1 (4 tokens each). blocks 1024..7935: 32x32 transposes.
__global__ __launch_bounds__(256) void prep_kernel(
    const float* __restrict__ x, const float* __restrict__ g,
    const float* __restrict__ b, u16* __restrict__ h,
    const float* __restrict__ in0, u16* __restrict__ out0,   // 768x2304
    const float* __restrict__ in1, u16* __restrict__ out1,   // 768x768
    const float* __restrict__ in2, u16* __restrict__ out2,   // 768x3072
    const float* __restrict__ in3, u16* __restrict__ out3) { // 3072x768
  const int tid = threadIdx.x;
  if (blockIdx.x < 1024) {
    // ---- LN1: one wave per token, f32 input ----
    int wave = tid >> 6, lane = tid & 63;
    int token = blockIdx.x * 4 + wave;
    float v[12];
    const float4* xr = (const float4*)(x + (size_t)token * DIM);
#pragma unroll
    for (int w = 0; w < 3; w++) {
      float4 q = xr[lane + w * 64];
      v[w * 4 + 0] = q.x; v[w * 4 + 1] = q.y; v[w * 4 + 2] = q.z; v[w * 4 + 3] = q.w;
    }
    float s = 0.f;
#pragma unroll
    for (int i = 0; i < 12; i++) s += v[i];
#pragma unroll
    for (int off = 32; off > 0; off >>= 1) s += __shfl_xor(s, off);
    float mu = s * (1.0f / DIM);
    float ss = 0.f;
#pragma unroll
    for (int i = 0; i < 12; i++) { float d = v[i] - mu; ss += d * d; }
#pragma unroll
    for (int off = 32; off > 0; off >>= 1) ss += __shfl_xor(ss, off);
    float rs = rsqrtf(ss * (1.0f / DIM) + 1e-5f);
    ushort4* orow = (ushort4*)(h + (size_t)token * DIM);
    const float4* g4 = (const float4*)g;
    const float4* b4 = (const float4*)b;
#pragma unroll
    for (int w = 0; w < 3; w++) {
      float4 gq = g4[lane + w * 64], bq = b4[lane + w * 64];
      ushort4 o;
      o.x = f2bf((v[w * 4 + 0] - mu) * rs * gq.x + bq.x);
      o.y = f2bf((v[w * 4 + 1] - mu) * rs * gq.y + bq.y);
      o.z = f2bf((v[w * 4 + 2] - mu) * rs * gq.z + bq.z);
      o.w = f2bf((v[w * 4 + 3] - mu) * rs * gq.w + bq.w);
      orow[lane + w * 64] = o;
    }
    return;
  }
  // ---- weight transpose ----
  __shared__ u16 t[32][33];
  int bid = blockIdx.x - 1024, rem;
  const float* in; u16* out; int R, C;
  if (bid < 1728)      { in = in0; out = out0; R = 768;  C = 2304; rem = bid; }
  else if (bid < 2304) { in = in1; out = out1; R = 768;  C = 768;  rem = bid - 1728; }
  else if (bid < 4608) { in = in2; out = out2; R = 768;  C = 3072; rem = bid - 2304; }
  else                 { in = in3; out = out3; R = 3072; C = 768;  rem = bid - 4608; }
  int c0 = (rem % (C / 32)) * 32, r0 = (rem / (C / 32)) * 32;
  int tx = tid & 31, ty = tid >> 5;
#pragma unroll
  for (int i = 0; i < 4; i++)
    t[ty + i * 8][tx] = f2bf(in[(size_t)(r0 + ty + i * 8) * C + c0 + tx]);
  __syncthreads();
#pragma unroll
  for (int i = 0; i < 4; i++)
    out[(size_t)(c0 + ty + i * 8) * R + r0 + tx] = t[tx][ty + i * 8];
}

// ---- LayerNorm (LN2): one wave per token, bf16 input -----------------------
__global__ __launch_bounds__(256) void ln_kernel(const u16* __restrict__ xin,
                                                 const float* __restrict__ g,
                                                 const float* __restrict__ b,
                                                 u16* __restrict__ out) {
  int wave = threadIdx.x >> 6, lane = threadIdx.x & 63;
  int token = blockIdx.x * 4 + wave;
  float v[12];
  const ushort4* xr = (const ushort4*)(xin + (size_t)token * DIM);
#pragma unroll
  for (int w = 0; w < 3; w++) {
    ushort4 q = xr[lane + w * 64];
    v[w * 4 + 0] = bf2f(q.x); v[w * 4 + 1] = bf2f(q.y);
    v[w * 4 + 2] = bf2f(q.z); v[w * 4 + 3] = bf2f(q.w);
  }
  float s = 0.f;
#pragma unroll
  for (int i = 0; i < 12; i++) s += v[i];
#pragma unroll
  for (int off = 32; off > 0; off >>= 1) s += __shfl_xor(s, off);
  float mu = s * (1.0f / DIM);
  float ss = 0.f;
#pragma unroll
  for (int i = 0; i < 12; i++) { float d = v[i] - mu; ss += d * d; }
#pragma unroll
  for (int off = 32; off > 0; off >>= 1) ss += __shfl_xor(ss, off);
  float rs = rsqrtf(ss * (1.0f / DIM) + 1e-5f);

  ushort4* orow = (ushort4*)(out + (size_t)token * DIM);
  const float4* g4 = (const float4*)g;
  const float4* b4 = (const float4*)b;
#pragma unroll
  for (int w = 0; w < 3; w++) {
    float4 gq = g4[lane + w * 64], bq = b4[lane + w * 64];
    ushort4 o;
    o.x = f2bf((v[w * 4 + 0] - mu) * rs * gq.x + bq.x);
    o.y = f2bf((v[w * 4 + 1] - mu) * rs * gq.y + bq.y);
    o.z = f2bf((v[w * 4 + 2] - mu) * rs * gq.z + bq.z);
    o.w = f2bf((v[w * 4 + 3] - mu) * rs * gq.w + bq.w);
    orow[lane + w * 64] = o;
  }
}

// ---- GEMM: C[M,N] = A[M,K] * BT[N,K]^T, bf16 in, fused epilogue ------------
// R13 structure: BK=64 as two stacked BK=32 panels, 2 barriers per iter.
// Flat grid, A-local XCD swizzle: by = b % (M/BM) (multiple of 8) -> all
// blocks sharing A-row-panels land on the same XCD; A stays in its L2.
// EPI: 0 = qkv: Q/K cols bf16 store; V cols (>=1536) packed transposed store
//      1 = +bias(f32) + resid(f32) -> bf16 store (proj -> x1 trunk)
//      2 = +bias(f32), exact gelu -> bf16 store (fc1)
//      3 = +bias(f32) + resid(bf16) -> F32 store (fc2 -> d_out)
template <int BM, int BN, int EPI>
__global__ __launch_bounds__(256, 3) void gemm_bt(
    const u16* __restrict__ A, const u16* __restrict__ BT,
    void* __restrict__ Cout, const float* __restrict__ bias,
    const void* __restrict__ resid, int M, int N, int K,
    u16* __restrict__ vtb) {
  constexpr int MT = BM / 32, NT = BN / 32;        // mfma tiles per wave
  constexpr int ACH = BM / 16;                     // A 16-row chunks per panel
  constexpr int CPW = (BM + BN) / 64;              // chunks per wave per panel
  __shared__ __align__(16) u16 Alds[2][BM * 32];   // two K-panels
  __shared__ __align__(16) u16 Blds[2][BN * 32];
  const int tid = threadIdx.x;
  const int lane = tid & 63, wave = tid >> 6;
  const int wr = wave >> 1, wc = wave & 1;
  const int nby = M / BM;                          // multiple of 8
  const int by = blockIdx.x % nby, bx = blockIdx.x / nby;
  const int bm = by * BM, bn = bx * BN;
  const int c16 = lane & 15, quad = lane >> 4;
  const int l4 = lane >> 2, lc = (lane & 3) * 8;

  f32x4 acc[MT][NT];
#pragma unroll
  for (int i = 0; i < MT; i++)
#pragma unroll
    for (int j = 0; j < NT; j++) acc[i][j] = (f32x4){0.f, 0.f, 0.f, 0.f};

  const u16* gsrc[CPW];
  u16* ldst[CPW];
  int hstep[CPW];                      // elems between panel 0 and 1 dests
#pragma unroll
  for (int c = 0; c < CPW; c++) {
    int chunk = wave * CPW + c;
    if (chunk < ACH) {
      gsrc[c] = A + (size_t)(bm + chunk * 16 + l4) * K + lc;
      ldst[c] = Alds[0] + chunk * 512;
      hstep[c] = BM * 32;
    } else {
      int bc = chunk - ACH;
      gsrc[c] = BT + (size_t)(bn + bc * 16 + l4) * K + lc;
      ldst[c] = Blds[0] + bc * 512;
      hstep[c] = BN * 32;
    }
  }

  for (int kk = 0; kk < K; kk += 64) {
    __syncthreads();                    // prior iteration's frag reads done
#pragma unroll
    for (int c = 0; c < CPW; c++) {
      async_copy16(gsrc[c] + kk, ldst[c]);
      async_copy16(gsrc[c] + kk + 32, ldst[c] + hstep[c]);
    }
    __syncthreads();                    // barrier drains vmcnt (LDS visible)
#pragma unroll
    for (int ks = 0; ks < 2; ks++) {
      short8 af[MT], bfr[NT];
#pragma unroll
      for (int mt = 0; mt < MT; mt++)
        af[mt] = *(const short8*)(Alds[ks] + (wr * (BM / 2) + mt * 16 + c16) * 32 + quad * 8);
#pragma unroll
      for (int nt = 0; nt < NT; nt++)
        bfr[nt] = *(const short8*)(Blds[ks] + (wc * (BN / 2) + nt * 16 + c16) * 32 + quad * 8);
#pragma unroll
      for (int mt = 0; mt < MT; mt++)
#pragma unroll
        for (int nt = 0; nt < NT; nt++)
          acc[mt][nt] = __builtin_amdgcn_mfma_f32_16x16x32_bf16(af[mt], bfr[nt],
                                                                acc[mt][nt], 0, 0, 0);
    }
  }

#pragma unroll
  for (int mt = 0; mt < MT; mt++) {
#pragma unroll
    for (int nt = 0; nt < NT; nt++) {
      int col = bn + wc * (BN / 2) + nt * 16 + c16;
      float bv = (EPI != 0) ? bias[col] : 0.f;
      int row0 = bm + wr * (BM / 2) + mt * 16 + quad * 4;
      if (EPI == 0 && col >= 2 * DIM) {
        // V columns: packed transposed store vt[(b*768+hd)][tok] (tok=row)
        int b = row0 >> 11;
        ushort4 pk;
        pk.x = f2bf(acc[mt][nt][0]); pk.y = f2bf(acc[mt][nt][1]);
        pk.z = f2bf(acc[mt][nt][2]); pk.w = f2bf(acc[mt][nt][3]);
        *(ushort4*)(vtb + ((size_t)b * DIM + col - 2 * DIM) * NSEQ + (row0 & 2047)) = pk;
        continue;
      }
#pragma unroll
      for (int r = 0; r < 4; r++) {
        int row = row0 + r;
        float vv = acc[mt][nt][r];
        if (EPI == 1) {
          vv += bv + ((const float*)resid)[(size_t)row * N + col];
          ((u16*)Cout)[(size_t)row * N + col] = f2bf(vv);
        } else if (EPI == 2) {
          vv += bv;
          vv = 0.5f * vv * (1.0f + erff(vv * 0.70710678118654752f));
          ((u16*)Cout)[(size_t)row * N + col] = f2bf(vv);
        } else if (EPI == 3) {
          vv += bv + bf2f(((const u16*)resid)[(size_t)row * N + col]);
          ((float*)Cout)[(size_t)row * N + col] = vv;     // f32 final output
        } else {
          ((u16*)Cout)[(size_t)row * N + col] = f2bf(vv);
        }
      }
    }
  }
}

// ---- flash attention v10 + head-major XCD swizzle --------------------------
// bh = blockIdx % 24 (24 = 2*NHEAD, multiple of 8): all 32 q-tiles of a head
// land on XCD bh%8; each XCD serves 3 heads = 1.5 MB KV -> L2-resident.
__global__ __launch_bounds__(256) void attn_kernel(const u16* __restrict__ qkv,
                                                   const u16* __restrict__ vt,
                                                   u16* __restrict__ o) {
  const int tid = threadIdx.x;
  const int lane = tid & 63, wave = tid >> 6;      // wave 0..3
  const int c16 = lane & 15, quad = lane >> 4;
  const int bh = blockIdx.x % (2 * NHEAD);         // head-major (XCD locality)
  const int qt = blockIdx.x / (2 * NHEAD);
  const int bb = bh / NHEAD, h = bh % NHEAD;
  __shared__ __align__(16) u16 Klds[2][64 * 64];   // [buf][key][d] swizzled
  __shared__ __align__(16) u16 Vtlds[2][64 * 64];  // [buf][d][key] swizzled
  __shared__ __align__(16) u16 Plds[4][16 * 64];   // per-wave P [q][key] swz
  const size_t base = (size_t)bb * NSEQ * QKV_N;
  const int q0 = qt * 64 + wave * 16;

  const u16* qp = qkv + base + (size_t)(q0 + c16) * QKV_N + h * HDIM;
  short8 qf0 = *(const short8*)(qp + quad * 8);
  short8 qf1 = *(const short8*)(qp + 32 + quad * 8);

  float Ls[4] = {0.f, 0.f, 0.f, 0.f};
  f32x4 Of[4];
#pragma unroll
  for (int dt = 0; dt < 4; dt++) Of[dt] = (f32x4){0.f, 0.f, 0.f, 0.f};

  const int srow = lane >> 3;
  const int schunk = (lane & 7) ^ srow;
  const int r0 = wave * 16;
  const u16* ksrc = qkv + base + (size_t)(r0 + srow) * QKV_N + DIM + h * HDIM + schunk * 8;
  const u16* vsrc = vt + ((size_t)bh * HDIM + r0 + srow) * NSEQ + schunk * 8;

  const int cswz0 = (quad ^ (c16 & 7)) * 8;        // frag-read swizzled chunks
  const int cswz1 = ((quad + 4) ^ (c16 & 7)) * 8;
  const float SC = 0.18033688011112042f;           // 0.125 * log2(e)

  // prologue: stage tile 0 into buffer 0
#pragma unroll
  for (int j = 0; j < 2; j++) {
    async_copy16(ksrc + (size_t)(8 * j) * QKV_N, Klds[0] + r0 * 64 + 8 * j * 64);
    async_copy16(vsrc + (size_t)(8 * j) * NSEQ, Vtlds[0] + r0 * 64 + 8 * j * 64);
  }

  for (int it = 0; it < NSEQ / 64; it++) {
    const int cur = it & 1;
    __syncthreads();   // drains DMA(it) + all waves done reading buf cur^1
    if (it + 1 < NSEQ / 64) {
      const int kt1 = (it + 1) * 64;
      u16* kd = Klds[cur ^ 1] + r0 * 64;
      u16* vd = Vtlds[cur ^ 1] + r0 * 64;
#pragma unroll
      for (int j = 0; j < 2; j++) {
        async_copy16(ksrc + (size_t)(kt1 + 8 * j) * QKV_N, kd + 8 * j * 64);
        async_copy16(vsrc + (size_t)(8 * j) * NSEQ + kt1, vd + 8 * j * 64);
      }
    }

    // S = Q K^T : 4 key-tiles of 16
    f32x4 S[4];
#pragma unroll
    for (int nt = 0; nt < 4; nt++) {
      S[nt] = (f32x4){0.f, 0.f, 0.f, 0.f};
      const u16* krow = Klds[cur] + (nt * 16 + c16) * 64;
      short8 ka = *(const short8*)(krow + cswz0);
      short8 kb = *(const short8*)(krow + cswz1);
      S[nt] = __builtin_amdgcn_mfma_f32_16x16x32_bf16(qf0, ka, S[nt], 0, 0, 0);
      S[nt] = __builtin_amdgcn_mfma_f32_16x16x32_bf16(qf1, kb, S[nt], 0, 0, 0);
    }

    // fixed-max softmax: p = 2^(S*SC); per-lane L partials, no shuffles
    u16* pl = Plds[wave];
    const int el = c16 & 7, ch = c16 >> 3;
#pragma unroll
    for (int r = 0; r < 4; r++) {
      float p0 = __builtin_amdgcn_exp2f(S[0][r] * SC);
      float p1 = __builtin_amdgcn_exp2f(S[1][r] * SC);
      float p2 = __builtin_amdgcn_exp2f(S[2][r] * SC);
      float p3 = __builtin_amdgcn_exp2f(S[3][r] * SC);
      Ls[r] += (p0 + p1) + (p2 + p3);
      u16* pr = pl + (quad * 4 + r) * 64;
      const int r7 = (quad * 4 + r) & 7;
      pr[((0 + ch) ^ r7) * 8 + el] = f2bf_trunc(p0);
      pr[((2 + ch) ^ r7) * 8 + el] = f2bf_trunc(p1);
      pr[((4 + ch) ^ r7) * 8 + el] = f2bf_trunc(p2);
      pr[((6 + ch) ^ r7) * 8 + el] = f2bf_trunc(p3);
    }
    // no barrier: Plds[wave] is same-wave only; DS ops execute in order

    // PV: A = P[16q x 64keys] (2 k-chunks), B^T = Vt[d][key] b128 frags
    short8 pf0 = *(const short8*)(pl + c16 * 64 + cswz0);
    short8 pf1 = *(const short8*)(pl + c16 * 64 + cswz1);
#pragma unroll
    for (int dt = 0; dt < 4; dt++) {
      const u16* vrow = Vtlds[cur] + (dt * 16 + c16) * 64;
      short8 va = *(const short8*)(vrow + cswz0);
      short8 vb = *(const short8*)(vrow + cswz1);
      Of[dt] = __builtin_amdgcn_mfma_f32_16x16x32_bf16(pf0, va, Of[dt], 0, 0, 0);
      Of[dt] = __builtin_amdgcn_mfma_f32_16x16x32_bf16(pf1, vb, Of[dt], 0, 0, 0);
    }
  }

  // row totals: reduce per-lane partials over the 16 lanes sharing each row
#pragma unroll
  for (int r = 0; r < 4; r++) {
    float t = Ls[r];
    t += __shfl_xor(t, 1); t += __shfl_xor(t, 2);
    t += __shfl_xor(t, 4); t += __shfl_xor(t, 8);
    Ls[r] = t;
  }

#pragma unroll
  for (int dt = 0; dt < 4; dt++)
#pragma unroll
    for (int r = 0; r < 4; r++) {
      int token = q0 + quad * 4 + r;
      float val = Of[dt][r] / Ls[r];
      o[(size_t)(bb * NSEQ + token) * DIM + h * HDIM + dt * 16 + c16] = f2bf(val);
    }
}

// ---------------------------------------------------------------------------
extern "C" void kernel_launch(void* const* d_in, const int* in_sizes, int n_in,
                              void* d_out, int out_size, void* d_ws, size_t ws_size,
                              hipStream_t stream) {
  (void)in_sizes; (void)n_in; (void)out_size; (void)ws_size;
  const float* x      = (const float*)d_in[0];
  const float* ln1_g  = (const float*)d_in[1];
  const float* ln1_b  = (const float*)d_in[2];
  const float* w_qkv  = (const float*)d_in[3];
  const float* w_proj = (const float*)d_in[4];
  const float* b_proj = (const float*)d_in[5];
  const float* ln2_g  = (const float*)d_in[6];
  const float* ln2_b  = (const float*)d_in[7];
  const float* w_fc1  = (const float*)d_in[8];
  const float* b_fc1  = (const float*)d_in[9];
  const float* w_fc2  = (const float*)d_in[10];
  const float* b_fc2  = (const float*)d_in[11];
  float* out = (float*)d_out;   // f32 output (reference dtype)

  // ---- workspace layout: ~55.8 MiB total ----
  char* p = (char*)d_ws;
  u16* h_bf   = (u16*)p; p += (size_t)TOKENS * DIM * 2;     //  h, then h2
  u16* qkv_bf = (u16*)p; p += (size_t)TOKENS * QKV_N * 2;
  u16* o_bf   = (u16*)p; p += (size_t)TOKENS * DIM * 2;
  u16* x1_bf  = (u16*)p; p += (size_t)TOKENS * DIM * 2;     //  trunk
  u16* wprojT = (u16*)p; p += (size_t)DIM * DIM * 2;
  u16* wfc1T  = (u16*)p; p += (size_t)HID * DIM * 2;
  u16* wfc2T  = (u16*)p; p += (size_t)DIM * HID * 2;
  u16* wqkvT  = (u16*)p; p += (size_t)QKV_N * DIM * 2;
  u16* vtb    = (u16*)p; p += (size_t)TOKENS * DIM * 2;     //  V transposed
  u16* m_bf   = qkv_bf;  // fc1 out [4096,3072] overlays dead [qkv|o] exactly

  prep_kernel<<<dim3(1024 + 6912), 256, 0, stream>>>(
      x, ln1_g, ln1_b, h_bf,
      w_qkv, wqkvT, w_proj, wprojT, w_fc1, wfc1T, w_fc2, wfc2T);

  gemm_bt<64, 128, 0><<<dim3((QKV_N / 128) * (TOKENS / 64)), 256, 0, stream>>>(
      h_bf, wqkvT, qkv_bf, nullptr, nullptr, TOKENS, QKV_N, DIM, vtb);
  attn_kernel<<<dim3(2 * NHEAD * (NSEQ / 64)), 256, 0, stream>>>(qkv_bf, vtb, o_bf);
  gemm_bt<64, 128, 1><<<dim3((DIM / 128) * (TOKENS / 64)), 256, 0, stream>>>(
      o_bf, wprojT, x1_bf, b_proj, x, TOKENS, DIM, DIM, nullptr);
  ln_kernel<<<TOKENS / 4, 256, 0, stream>>>(x1_bf, ln2_g, ln2_b, h_bf);
  gemm_bt<128, 128, 2><<<dim3((HID / 128) * (TOKENS / 128)), 256, 0, stream>>>(
      h_bf, wfc1T, m_bf, b_fc1, nullptr, TOKENS, HID, DIM, nullptr);
  gemm_bt<64, 128, 3><<<dim3((DIM / 128) * (TOKENS / 64)), 256, 0, stream>>>(
      m_bf, wfc2T, out, b_fc2, x1_bf, TOKENS, DIM, HID, nullptr);
}